// Round 9
// baseline (433.534 us; speedup 1.0000x reference)
//
#include <hip/hip_runtime.h>
#include <math.h>

#define BS 16
#define EMB 512
#define NSTK 32
#define NPNT 64
#define SPO 1024
#define DNO 1024
#define NS2 16
#define BNEPS 1e-5f

typedef __attribute__((ext_vector_type(8))) short short8;
typedef __attribute__((ext_vector_type(4))) float f32x4;

#define WS_FPS_OFF 0
#define WS_KNN_OFF 4096
#define WS_WT_OFF 8192  // bf16 W_T[3][64][1024][8] = 3145728 B

__device__ __forceinline__ float gelu_exact(float x) {
  return 0.5f * x * (1.0f + erff(x * 0.70710678118654752440f));
}

// f32 -> bf16 (RNE), header-independent. Finite inputs only (holds here:
// inputs are random normals / scaled weights; no NaN/Inf path upstream).
__device__ __forceinline__ unsigned short f2b(float f) {
  unsigned int u = __float_as_uint(f);
  u += 0x7fffu + ((u >> 16) & 1u);
  return (unsigned short)(u >> 16);
}

// ---------------------------------------------------------------------------
// K0: dn_w [1024][512][3] f32 -> W_T [3][c/8][1024][8] bf16 (fragment-packed)
// ---------------------------------------------------------------------------
__global__ __launch_bounds__(256) void k0_wt(
    const float* __restrict__ dn_w, unsigned short* __restrict__ wt) {
  int gid = blockIdx.x * 256 + threadIdx.x;  // 393216 total
  const float4 v = reinterpret_cast<const float4*>(dn_w)[gid];
  float vv[4] = {v.x, v.y, v.z, v.w};
#pragma unroll
  for (int i = 0; i < 4; ++i) {
    int flat = gid * 4 + i;
    int o = flat / 1536, rem = flat % 1536;
    int c = rem / 3, k = rem % 3;
    wt[((size_t)(k * 64 + (c >> 3)) * 1024 + o) * 8 + (c & 7)] = f2b(vv[i]);
  }
}

// ---------------------------------------------------------------------------
// K1: per-batch FPS + kNN + stk_sampled.  (unchanged from f32 baseline)
// ---------------------------------------------------------------------------
__global__ __launch_bounds__(256) void k1_fps_knn(
    const float* __restrict__ stk,   // [BS][EMB][NSTK]
    float* __restrict__ out_stk,     // [BS][EMB][NS2]
    int* __restrict__ fps_idx,       // [BS][NS2]
    int* __restrict__ knn_sel) {     // [BS][NS2][2]
  __shared__ float xc[NSTK][129];
  __shared__ float Dfps[NSTK][NSTK];
  __shared__ float Dot[NSTK][NSTK + 1];
  __shared__ int fps_l[NS2];
  __shared__ int knn_all[NSTK][2];
  const int b = blockIdx.x, tid = threadIdx.x;
  const float* xb = stk + (size_t)b * EMB * NSTK;

  float accd[4] = {0.f, 0.f, 0.f, 0.f};
  float accp[4] = {0.f, 0.f, 0.f, 0.f};
  for (int ch = 0; ch < EMB / 128; ++ch) {
    __syncthreads();
    for (int e = 0; e < 16; ++e) {
      int idx = e * 256 + tid;
      int cl = idx >> 5, n = idx & 31;
      xc[n][cl] = xb[(ch * 128 + cl) * NSTK + n];
    }
    __syncthreads();
    for (int e = 0; e < 4; ++e) {
      int pid = e * 256 + tid;
      int n = pid >> 5, m = pid & 31;
      float d = accd[e], p = accp[e];
      for (int c = 0; c < 128; ++c) {
        float a = xc[n][c], bb = xc[m][c];
        float df = a - bb;
        d += df * df;
        p += a * bb;
      }
      accd[e] = d;
      accp[e] = p;
    }
  }
  __syncthreads();
  for (int e = 0; e < 4; ++e) {
    int pid = e * 256 + tid;
    int n = pid >> 5, m = pid & 31;
    Dfps[n][m] = accd[e];
    Dot[n][m] = accp[e];
  }
  __syncthreads();

  if (tid < 64) {
    const int lane = tid;
    const bool act = lane < NSTK;
    float dist = 1e10f;
    int far = 0;
    for (int k = 0; k < NS2; ++k) {
      if (lane == 0) fps_l[k] = far;
      float d = Dfps[act ? lane : 0][far];
      dist = fminf(dist, d);
      float v = act ? dist : -1e30f;
      int vi = act ? lane : 1000;
      for (int off = 32; off >= 1; off >>= 1) {
        float ov = __shfl_xor(v, off);
        int oi = __shfl_xor(vi, off);
        if (ov > v || (ov == v && oi < vi)) { v = ov; vi = oi; }
      }
      far = vi;
    }
  }
  __syncthreads();

  if (tid < NSTK) {
    int n = tid;
    float xxn = Dot[n][n];
    float v1 = -1e30f, v2 = -1e30f;
    int i1 = 0, i2 = 0;
    for (int m = 0; m < NSTK; ++m) {
      float pd = 2.f * Dot[n][m] - xxn - Dot[m][m];
      if (pd > v1) { v2 = v1; i2 = i1; v1 = pd; i1 = m; }
      else if (pd > v2) { v2 = pd; i2 = m; }
    }
    knn_all[n][0] = i1;
    knn_all[n][1] = i2;
  }
  __syncthreads();
  if (tid < NS2) fps_idx[b * NS2 + tid] = fps_l[tid];
  if (tid < NS2 * 2) {
    int i = tid >> 1, j = tid & 1;
    knn_sel[(b * NS2 + i) * 2 + j] = knn_all[fps_l[i]][j];
  }
  for (int e = 0; e < (EMB * NS2) / 256; ++e) {
    int idx = e * 256 + tid;
    int c = idx >> 4, i = idx & 15;
    out_stk[(size_t)b * EMB * NS2 + idx] = xb[c * NSTK + fps_l[i]];
  }
}

// ---------------------------------------------------------------------------
// K2: sparse branch (unchanged f32 baseline)
// ---------------------------------------------------------------------------
__global__ __launch_bounds__(256) void k2_sparse(
    const float* __restrict__ sparse_fea, const float* __restrict__ sp_w,
    const float* __restrict__ sp_b, const float* __restrict__ sp_g,
    const float* __restrict__ sp_be, const float* __restrict__ sp_m,
    const float* __restrict__ sp_v, const int* __restrict__ knn_sel,
    float* __restrict__ out_sf) {
  __shared__ float smax[64][33];
  __shared__ float wl[64][132];
  __shared__ int kk[32][2];
  const int ot = blockIdx.x, g = blockIdx.y, tid = threadIdx.x;
  const int og = tid & 31, clg = tid >> 5;
  if (tid < 64) {
    int cl = tid >> 1, j = tid & 1;
    int col = g * 32 + cl, b = col >> 4, i = col & 15;
    kk[cl][j] = knn_sel[(b * NS2 + i) * 2 + j];
  }
  float acc[4][4] = {};
  for (int ch = 0; ch < 8; ++ch) {
    __syncthreads();
    for (int e = 0; e < 8; ++e) {
      int idx = e * 256 + tid;
      int cc = idx >> 5, cl = idx & 31;
      int col = g * 32 + cl, b = col >> 4;
      int c = ch * 64 + cc;
      const float* sp = sparse_fea + ((size_t)b * EMB + c) * NSTK;
      smax[cc][cl] = fmaxf(sp[kk[cl][0]], sp[kk[cl][1]]);
    }
    for (int e = 0; e < 32; ++e) {
      int idx = e * 256 + tid;
      int o = idx >> 6, cc = idx & 63;
      wl[cc][o] = sp_w[(size_t)(ot * 128 + o) * EMB + ch * 64 + cc];
    }
    __syncthreads();
    for (int cc = 0; cc < 64; ++cc) {
      const float4 w4 = *(const float4*)&wl[cc][og * 4];
      float wv[4] = {w4.x, w4.y, w4.z, w4.w};
      float xv[4];
#pragma unroll
      for (int q = 0; q < 4; ++q) xv[q] = smax[cc][clg + 8 * q];
#pragma unroll
      for (int r = 0; r < 4; ++r)
#pragma unroll
        for (int q = 0; q < 4; ++q) acc[r][q] += wv[r] * xv[q];
    }
  }
#pragma unroll
  for (int r = 0; r < 4; ++r) {
    int o = ot * 128 + og * 4 + r;
    float sc = sp_g[o] * rsqrtf(sp_v[o] + BNEPS);
    float mm = sp_m[o], be = sp_be[o], bi = sp_b[o];
#pragma unroll
    for (int q = 0; q < 4; ++q) {
      int col = g * 32 + clg + 8 * q, b = col >> 4, i = col & 15;
      float x = (acc[r][q] + bi - mm) * sc + be;
      out_sf[((size_t)b * SPO + o) * NS2 + i] = gelu_exact(x);
    }
  }
}

// ---------------------------------------------------------------------------
// K3: dense branch via bf16 MFMA (16x16x32).
// Block: (oc, ii-grp of 4, b); 512 thr = 8 waves = (ii 0..3) x (m-half 0..1).
// Per wave: 64 o x 64 cols, cols = interleaved (t, j): col = 2t+j.
// X staged parity-split pos-major: XE[t][cc] = x[2t], XO[u+1][cc] = x[2u+1];
// taps (x[2t-1], x[2t], x[2t+1]) = rows (XO[t], XE[t], XO[t+1]) -> per-lane
// row-base shifts only; 8-cc fragment elems stay 16B-contiguous (b128).
// A fragment-packed in LDS from W_T (linear, conflict-free).
// Epilogue: folded BN + exact GELU + neighbor-max via __shfl_xor(.,1).
// ---------------------------------------------------------------------------
__global__ __launch_bounds__(512, 4) void k3_dense_mfma(
    const float* __restrict__ dense_fea,     // [BS][EMB][2048]
    const unsigned short* __restrict__ wt,   // W_T bf16 [3][64][1024][8]
    const float* __restrict__ dn_b, const float* __restrict__ dn_g,
    const float* __restrict__ dn_be, const float* __restrict__ dn_m,
    const float* __restrict__ dn_v, const int* __restrict__ knn_sel,
    float* __restrict__ out_df) {            // [BS][DNO][512]
  __shared__ unsigned short WL[24 * 512];      // 24 frags x 64 lanes x 8
  __shared__ unsigned short XE[4][2][32][40];  // [ii][j][t][cc], pad 40
  __shared__ unsigned short XO[4][2][34][40];  // row u+1 = x[2u+1]; row0 = pad
  __shared__ float2 bnp[128];                  // (scale, shift) per o_local
  __shared__ int sel[4][2];

  const int oc = blockIdx.x, iig = blockIdx.y, b = blockIdx.z;
  const int tid = threadIdx.x;
  const int lane = tid & 63, wave = tid >> 6;
  const int mh = wave & 1, ii_w = wave >> 1;
  const int g = lane >> 4, cl = lane & 15, j = cl & 1, thalf = cl >> 1;

  if (tid < 8) {
    int ii = tid >> 1, jj = tid & 1;
    sel[ii][jj] = knn_sel[(b * NS2 + iig * 4 + ii) * 2 + jj];
  }
  if (tid < 320) {  // zero O pad row (x[-1])
    int ii = tid / 80, rest = tid % 80;
    XO[ii][rest / 40][0][rest % 40] = 0;
  }
  if (tid < 128) {
    int o = oc * 128 + tid;
    float sc = dn_g[o] * rsqrtf(dn_v[o] + BNEPS);
    bnp[tid] = make_float2(sc, (dn_b[o] - dn_m[o]) * sc + dn_be[o]);
  }

  const short8* wt8 = reinterpret_cast<const short8*>(wt);
  f32x4 acc[4][4] = {};

  for (int ch = 0; ch < 16; ++ch) {
    __syncthreads();  // iter0: sel/zero/bnp visible; later: compute done
    // --- A stage: W_T -> WL, fragment-ready, linear (conflict-free) ---
#pragma unroll
    for (int i = 0; i < 3; ++i) {
      int u = i * 512 + tid;  // 0..1535
      int f = u >> 6, l = u & 63;
      int k = f >> 3, mg = f & 7, gg = l >> 4, r = l & 15;
      short8 wv = wt8[(size_t)(k * 64 + ch * 4 + gg) * 1024 + oc * 128 +
                      mg * 16 + r];
      *reinterpret_cast<short8*>(&WL[u * 8]) = wv;
    }
    // --- X stage: parity-split transpose (scalar u16 writes) ---
#pragma unroll
    for (int i = 0; i < 8; ++i) {
      int u = i * 512 + tid;  // 0..4095
      int pos4 = u & 15, cc = (u >> 4) & 31, jj = (u >> 9) & 1, ii = u >> 10;
      const float4 xv = *reinterpret_cast<const float4*>(
          &dense_fea[((size_t)b * EMB + ch * 32 + cc) * 2048 +
                     sel[ii][jj] * 64 + pos4 * 4]);
      int p2 = pos4 * 2;
      XE[ii][jj][p2][cc] = f2b(xv.x);
      XO[ii][jj][p2 + 1][cc] = f2b(xv.y);
      XE[ii][jj][p2 + 1][cc] = f2b(xv.z);
      XO[ii][jj][p2 + 2][cc] = f2b(xv.w);
    }
    __syncthreads();
    // --- MFMA: 3 taps x 4 m x 4 n ---
    const unsigned short* XEb = &XE[ii_w][j][0][0];
    const unsigned short* XOb = &XO[ii_w][j][0][0];
#pragma unroll
    for (int tap = 0; tap < 3; ++tap) {
      short8 bq[4];
#pragma unroll
      for (int n = 0; n < 4; ++n) {
        int t = n * 8 + thalf;
        const unsigned short* src =
            (tap == 1) ? (XEb + t * 40 + 8 * g)
                       : (XOb + (tap == 0 ? t : t + 1) * 40 + 8 * g);
        bq[n] = *reinterpret_cast<const short8*>(src);
      }
#pragma unroll
      for (int m = 0; m < 4; ++m) {
        short8 aq = *reinterpret_cast<const short8*>(
            &WL[(tap * 8 + mh * 4 + m) * 512 + lane * 8]);
#pragma unroll
        for (int n = 0; n < 4; ++n)
          acc[m][n] =
              __builtin_amdgcn_mfma_f32_16x16x32_bf16(aq, bq[n], acc[m][n],
                                                      0, 0, 0);
      }
    }
  }

  // --- Epilogue: BN + GELU + neighbor-max (lane^1) ---
#pragma unroll
  for (int m = 0; m < 4; ++m) {
#pragma unroll
    for (int n = 0; n < 4; ++n) {
#pragma unroll
      for (int r = 0; r < 4; ++r) {
        int ol = mh * 64 + m * 16 + g * 4 + r;
        float2 p = bnp[ol];
        float v = acc[m][n][r] * p.x + p.y;
        float ge = gelu_exact(v);
        float gm = fmaxf(ge, __shfl_xor(ge, 1));
        if (j == 0) {
          out_df[((size_t)b * DNO + oc * 128 + ol) * 512 +
                 (iig * 4 + ii_w) * 32 + n * 8 + thalf] = gm;
        }
      }
    }
  }
}

extern "C" void kernel_launch(void* const* d_in, const int* in_sizes, int n_in,
                              void* d_out, int out_size, void* d_ws,
                              size_t ws_size, hipStream_t stream) {
  (void)in_sizes; (void)n_in; (void)out_size; (void)ws_size;
  const float* sparse_fea = (const float*)d_in[0];
  const float* dense_fea = (const float*)d_in[1];
  const float* stk_fea = (const float*)d_in[2];
  const float* sp_w = (const float*)d_in[3];
  const float* sp_b = (const float*)d_in[4];
  const float* sp_g = (const float*)d_in[5];
  const float* sp_be = (const float*)d_in[6];
  const float* sp_m = (const float*)d_in[7];
  const float* sp_v = (const float*)d_in[8];
  const float* dn_w = (const float*)d_in[9];
  const float* dn_b = (const float*)d_in[10];
  const float* dn_g = (const float*)d_in[11];
  const float* dn_be = (const float*)d_in[12];
  const float* dn_m = (const float*)d_in[13];
  const float* dn_v = (const float*)d_in[14];

  float* out = (float*)d_out;
  float* out_sf = out;                                   // [16][1024][16]
  float* out_df = out + (size_t)BS * SPO * NS2;          // [16][1024][512]
  float* out_stk = out_df + (size_t)BS * DNO * 512;      // [16][512][16]

  int* fps_idx = (int*)((char*)d_ws + WS_FPS_OFF);
  int* knn_sel = (int*)((char*)d_ws + WS_KNN_OFF);
  unsigned short* wt = (unsigned short*)((char*)d_ws + WS_WT_OFF);

  hipLaunchKernelGGL(k0_wt, dim3(1536), dim3(256), 0, stream, dn_w, wt);
  hipLaunchKernelGGL(k1_fps_knn, dim3(BS), dim3(256), 0, stream,
                     stk_fea, out_stk, fps_idx, knn_sel);
  hipLaunchKernelGGL(k2_sparse, dim3(8, 8), dim3(256), 0, stream,
                     sparse_fea, sp_w, sp_b, sp_g, sp_be, sp_m, sp_v, knn_sel,
                     out_sf);
  hipLaunchKernelGGL(k3_dense_mfma, dim3(8, 4, BS), dim3(512), 0, stream,
                     dense_fea, wt, dn_b, dn_g, dn_be, dn_m, dn_v, knn_sel,
                     out_df);
}

// Round 12
// 332.585 us; speedup vs baseline: 1.3035x; 1.3035x over previous
//
#include <hip/hip_runtime.h>
#include <math.h>

#define BS 16
#define EMB 512
#define NSTK 32
#define NPNT 64
#define SPO 1024
#define DNO 1024
#define NS2 16
#define BNEPS 1e-5f

typedef __attribute__((ext_vector_type(8))) short short8;
typedef __attribute__((ext_vector_type(4))) float f32x4;

#define WS_FPS_OFF 0
#define WS_KNN_OFF 4096
#define WS_WT_OFF 8192  // bf16 W_T[3][64][1024][8] = 3145728 B

__device__ __forceinline__ float gelu_exact(float x) {
  return 0.5f * x * (1.0f + erff(x * 0.70710678118654752440f));
}

// f32 -> bf16 (RNE), header-independent.
__device__ __forceinline__ unsigned short f2b(float f) {
  unsigned int u = __float_as_uint(f);
  u += 0x7fffu + ((u >> 16) & 1u);
  return (unsigned short)(u >> 16);
}

// ---------------------------------------------------------------------------
// K0: dn_w [1024][512][3] f32 -> W_T [3][c/8][1024][8] bf16 (fragment-packed)
// ---------------------------------------------------------------------------
__global__ __launch_bounds__(256) void k0_wt(
    const float* __restrict__ dn_w, unsigned short* __restrict__ wt) {
  int gid = blockIdx.x * 256 + threadIdx.x;  // 393216 total
  const float4 v = reinterpret_cast<const float4*>(dn_w)[gid];
  float vv[4] = {v.x, v.y, v.z, v.w};
#pragma unroll
  for (int i = 0; i < 4; ++i) {
    int flat = gid * 4 + i;
    int o = flat / 1536, rem = flat % 1536;
    int c = rem / 3, k = rem % 3;
    wt[((size_t)(k * 64 + (c >> 3)) * 1024 + o) * 8 + (c & 7)] = f2b(vv[i]);
  }
}

// ---------------------------------------------------------------------------
// K1: per-batch FPS + kNN + stk_sampled.  (unchanged, HW-validated)
// ---------------------------------------------------------------------------
__global__ __launch_bounds__(256) void k1_fps_knn(
    const float* __restrict__ stk,   // [BS][EMB][NSTK]
    float* __restrict__ out_stk,     // [BS][EMB][NS2]
    int* __restrict__ fps_idx,       // [BS][NS2]
    int* __restrict__ knn_sel) {     // [BS][NS2][2]
  __shared__ float xc[NSTK][129];
  __shared__ float Dfps[NSTK][NSTK];
  __shared__ float Dot[NSTK][NSTK + 1];
  __shared__ int fps_l[NS2];
  __shared__ int knn_all[NSTK][2];
  const int b = blockIdx.x, tid = threadIdx.x;
  const float* xb = stk + (size_t)b * EMB * NSTK;

  float accd[4] = {0.f, 0.f, 0.f, 0.f};
  float accp[4] = {0.f, 0.f, 0.f, 0.f};
  for (int ch = 0; ch < EMB / 128; ++ch) {
    __syncthreads();
    for (int e = 0; e < 16; ++e) {
      int idx = e * 256 + tid;
      int cl = idx >> 5, n = idx & 31;
      xc[n][cl] = xb[(ch * 128 + cl) * NSTK + n];
    }
    __syncthreads();
    for (int e = 0; e < 4; ++e) {
      int pid = e * 256 + tid;
      int n = pid >> 5, m = pid & 31;
      float d = accd[e], p = accp[e];
      for (int c = 0; c < 128; ++c) {
        float a = xc[n][c], bb = xc[m][c];
        float df = a - bb;
        d += df * df;
        p += a * bb;
      }
      accd[e] = d;
      accp[e] = p;
    }
  }
  __syncthreads();
  for (int e = 0; e < 4; ++e) {
    int pid = e * 256 + tid;
    int n = pid >> 5, m = pid & 31;
    Dfps[n][m] = accd[e];
    Dot[n][m] = accp[e];
  }
  __syncthreads();

  if (tid < 64) {
    const int lane = tid;
    const bool act = lane < NSTK;
    float dist = 1e10f;
    int far = 0;
    for (int k = 0; k < NS2; ++k) {
      if (lane == 0) fps_l[k] = far;
      float d = Dfps[act ? lane : 0][far];
      dist = fminf(dist, d);
      float v = act ? dist : -1e30f;
      int vi = act ? lane : 1000;
      for (int off = 32; off >= 1; off >>= 1) {
        float ov = __shfl_xor(v, off);
        int oi = __shfl_xor(vi, off);
        if (ov > v || (ov == v && oi < vi)) { v = ov; vi = oi; }
      }
      far = vi;
    }
  }
  __syncthreads();

  if (tid < NSTK) {
    int n = tid;
    float xxn = Dot[n][n];
    float v1 = -1e30f, v2 = -1e30f;
    int i1 = 0, i2 = 0;
    for (int m = 0; m < NSTK; ++m) {
      float pd = 2.f * Dot[n][m] - xxn - Dot[m][m];
      if (pd > v1) { v2 = v1; i2 = i1; v1 = pd; i1 = m; }
      else if (pd > v2) { v2 = pd; i2 = m; }
    }
    knn_all[n][0] = i1;
    knn_all[n][1] = i2;
  }
  __syncthreads();
  if (tid < NS2) fps_idx[b * NS2 + tid] = fps_l[tid];
  if (tid < NS2 * 2) {
    int i = tid >> 1, j = tid & 1;
    knn_sel[(b * NS2 + i) * 2 + j] = knn_all[fps_l[i]][j];
  }
  for (int e = 0; e < (EMB * NS2) / 256; ++e) {
    int idx = e * 256 + tid;
    int c = idx >> 4, i = idx & 15;
    out_stk[(size_t)b * EMB * NS2 + idx] = xb[c * NSTK + fps_l[i]];
  }
}

// ---------------------------------------------------------------------------
// K2a: sparse branch, split-K partial GEMM. Grid (8 ot, 8 g, 8 ks) = 512
// blocks (was 64 -> occupancy 2.9%, VALUBusy 1.8%, 149us: latency-bound).
// Each block: K-slice of 64 channels, 128 o x 32 cols, partials -> scratch.
// ---------------------------------------------------------------------------
__global__ __launch_bounds__(256) void k2a_partial(
    const float* __restrict__ sparse_fea, const float* __restrict__ sp_w,
    const int* __restrict__ knn_sel,
    float* __restrict__ part) {  // [8][1024][256] f32 (in d_out scratch)
  __shared__ float smax[64][33];
  __shared__ float wl[64][132];
  __shared__ int kk[32][2];
  const int ot = blockIdx.x, g = blockIdx.y, ks = blockIdx.z;
  const int tid = threadIdx.x;
  const int og = tid & 31, clg = tid >> 5;
  if (tid < 64) {
    int cl = tid >> 1, j = tid & 1;
    int col = g * 32 + cl, b = col >> 4, i = col & 15;
    kk[cl][j] = knn_sel[(b * NS2 + i) * 2 + j];
  }
  __syncthreads();
  for (int e = 0; e < 8; ++e) {
    int idx = e * 256 + tid;
    int cc = idx >> 5, cl = idx & 31;
    int col = g * 32 + cl, b = col >> 4;
    int c = ks * 64 + cc;
    const float* sp = sparse_fea + ((size_t)b * EMB + c) * NSTK;
    smax[cc][cl] = fmaxf(sp[kk[cl][0]], sp[kk[cl][1]]);
  }
  for (int e = 0; e < 32; ++e) {
    int idx = e * 256 + tid;
    int o = idx >> 6, cc = idx & 63;
    wl[cc][o] = sp_w[(size_t)(ot * 128 + o) * EMB + ks * 64 + cc];
  }
  __syncthreads();
  float acc[4][4] = {};
  for (int cc = 0; cc < 64; ++cc) {
    const float4 w4 = *(const float4*)&wl[cc][og * 4];
    float wv[4] = {w4.x, w4.y, w4.z, w4.w};
    float xv[4];
#pragma unroll
    for (int q = 0; q < 4; ++q) xv[q] = smax[cc][clg + 8 * q];
#pragma unroll
    for (int r = 0; r < 4; ++r)
#pragma unroll
      for (int q = 0; q < 4; ++q) acc[r][q] += wv[r] * xv[q];
  }
#pragma unroll
  for (int r = 0; r < 4; ++r) {
    int o = ot * 128 + og * 4 + r;
#pragma unroll
    for (int q = 0; q < 4; ++q) {
      int col = g * 32 + clg + 8 * q;
      part[((size_t)ks * 1024 + o) * 256 + col] = acc[r][q];
    }
  }
}

// ---------------------------------------------------------------------------
// K2b: reduce 8 partials + bias/BN/GELU -> out_sf. Grid 1024 x 256 thr.
// ---------------------------------------------------------------------------
__global__ __launch_bounds__(256) void k2b_reduce(
    const float* __restrict__ part, const float* __restrict__ sp_b,
    const float* __restrict__ sp_g, const float* __restrict__ sp_be,
    const float* __restrict__ sp_m, const float* __restrict__ sp_v,
    float* __restrict__ out_sf) {
  int gid = blockIdx.x * 256 + threadIdx.x;  // o*256 + col
  int o = gid >> 8, col = gid & 255;
  float s = 0.f;
#pragma unroll
  for (int ks = 0; ks < 8; ++ks) s += part[(size_t)ks * 262144 + gid];
  float sc = sp_g[o] * rsqrtf(sp_v[o] + BNEPS);
  float x = (s + sp_b[o] - sp_m[o]) * sc + sp_be[o];
  int b = col >> 4, i = col & 15;
  out_sf[((size_t)b * SPO + o) * NS2 + i] = gelu_exact(x);
}

// ---------------------------------------------------------------------------
// K3: dense branch via bf16 MFMA (16x16x32). Structure HW-validated (r9).
// NEW: XCD-group swizzle — 1D grid 512; oc = P>>6, grp = P&63 so the 8 oc
// blocks sharing one (iig,b) X-slice get the same P%8 -> same XCD -> L2
// sharing (r9: FETCH 195MB = 3x input because default round-robin put them
// on 8 different XCDs).
// ---------------------------------------------------------------------------
__global__ __launch_bounds__(512, 4) void k3_dense_mfma(
    const float* __restrict__ dense_fea,     // [BS][EMB][2048]
    const unsigned short* __restrict__ wt,   // W_T bf16 [3][64][1024][8]
    const float* __restrict__ dn_b, const float* __restrict__ dn_g,
    const float* __restrict__ dn_be, const float* __restrict__ dn_m,
    const float* __restrict__ dn_v, const int* __restrict__ knn_sel,
    float* __restrict__ out_df) {            // [BS][DNO][512]
  __shared__ unsigned short WL[24 * 512];      // 24 frags x 64 lanes x 8
  __shared__ unsigned short XE[4][2][32][40];  // [ii][j][t][cc], pad 40
  __shared__ unsigned short XO[4][2][34][40];  // row u+1 = x[2u+1]; row0 = pad
  __shared__ float2 bnp[128];                  // (scale, shift) per o_local
  __shared__ int sel[4][2];

  const int P = blockIdx.x;
  const int oc = P >> 6, grp = P & 63;
  const int iig = grp & 3, b = grp >> 2;
  const int tid = threadIdx.x;
  const int lane = tid & 63, wave = tid >> 6;
  const int mh = wave & 1, ii_w = wave >> 1;
  const int g = lane >> 4, cl = lane & 15, j = cl & 1, thalf = cl >> 1;

  if (tid < 8) {
    int ii = tid >> 1, jj = tid & 1;
    sel[ii][jj] = knn_sel[(b * NS2 + iig * 4 + ii) * 2 + jj];
  }
  if (tid < 320) {  // zero O pad row (x[-1])
    int ii = tid / 80, rest = tid % 80;
    XO[ii][rest / 40][0][rest % 40] = 0;
  }
  if (tid < 128) {
    int o = oc * 128 + tid;
    float sc = dn_g[o] * rsqrtf(dn_v[o] + BNEPS);
    bnp[tid] = make_float2(sc, (dn_b[o] - dn_m[o]) * sc + dn_be[o]);
  }

  const short8* wt8 = reinterpret_cast<const short8*>(wt);
  f32x4 acc[4][4] = {};

  for (int ch = 0; ch < 16; ++ch) {
    __syncthreads();  // iter0: sel/zero/bnp visible; later: compute done
    // --- A stage: W_T -> WL, fragment-ready, linear (conflict-free) ---
#pragma unroll
    for (int i = 0; i < 3; ++i) {
      int u = i * 512 + tid;  // 0..1535
      int f = u >> 6, l = u & 63;
      int k = f >> 3, mg = f & 7, gg = l >> 4, r = l & 15;
      short8 wv = wt8[(size_t)(k * 64 + ch * 4 + gg) * 1024 + oc * 128 +
                      mg * 16 + r];
      *reinterpret_cast<short8*>(&WL[u * 8]) = wv;
    }
    // --- X stage: parity-split transpose (scalar u16 writes) ---
#pragma unroll
    for (int i = 0; i < 8; ++i) {
      int u = i * 512 + tid;  // 0..4095
      int pos4 = u & 15, cc = (u >> 4) & 31, jj = (u >> 9) & 1, ii = u >> 10;
      const float4 xv = *reinterpret_cast<const float4*>(
          &dense_fea[((size_t)b * EMB + ch * 32 + cc) * 2048 +
                     sel[ii][jj] * 64 + pos4 * 4]);
      int p2 = pos4 * 2;
      XE[ii][jj][p2][cc] = f2b(xv.x);
      XO[ii][jj][p2 + 1][cc] = f2b(xv.y);
      XE[ii][jj][p2 + 1][cc] = f2b(xv.z);
      XO[ii][jj][p2 + 2][cc] = f2b(xv.w);
    }
    __syncthreads();
    // --- MFMA: 3 taps x 4 m x 4 n ---
    const unsigned short* XEb = &XE[ii_w][j][0][0];
    const unsigned short* XOb = &XO[ii_w][j][0][0];
#pragma unroll
    for (int tap = 0; tap < 3; ++tap) {
      short8 bq[4];
#pragma unroll
      for (int n = 0; n < 4; ++n) {
        int t = n * 8 + thalf;
        const unsigned short* src =
            (tap == 1) ? (XEb + t * 40 + 8 * g)
                       : (XOb + (tap == 0 ? t : t + 1) * 40 + 8 * g);
        bq[n] = *reinterpret_cast<const short8*>(src);
      }
#pragma unroll
      for (int m = 0; m < 4; ++m) {
        short8 aq = *reinterpret_cast<const short8*>(
            &WL[(tap * 8 + mh * 4 + m) * 512 + lane * 8]);
#pragma unroll
        for (int n = 0; n < 4; ++n)
          acc[m][n] =
              __builtin_amdgcn_mfma_f32_16x16x32_bf16(aq, bq[n], acc[m][n],
                                                      0, 0, 0);
      }
    }
  }

  // --- Epilogue: BN + GELU + neighbor-max (lane^1) ---
#pragma unroll
  for (int m = 0; m < 4; ++m) {
#pragma unroll
    for (int n = 0; n < 4; ++n) {
#pragma unroll
      for (int r = 0; r < 4; ++r) {
        int ol = mh * 64 + m * 16 + g * 4 + r;
        float2 p = bnp[ol];
        float v = acc[m][n][r] * p.x + p.y;
        float ge = gelu_exact(v);
        float gm = fmaxf(ge, __shfl_xor(ge, 1));
        if (j == 0) {
          out_df[((size_t)b * DNO + oc * 128 + ol) * 512 +
                 (iig * 4 + ii_w) * 32 + n * 8 + thalf] = gm;
        }
      }
    }
  }
}

extern "C" void kernel_launch(void* const* d_in, const int* in_sizes, int n_in,
                              void* d_out, int out_size, void* d_ws,
                              size_t ws_size, hipStream_t stream) {
  (void)in_sizes; (void)n_in; (void)out_size; (void)ws_size;
  const float* sparse_fea = (const float*)d_in[0];
  const float* dense_fea = (const float*)d_in[1];
  const float* stk_fea = (const float*)d_in[2];
  const float* sp_w = (const float*)d_in[3];
  const float* sp_b = (const float*)d_in[4];
  const float* sp_g = (const float*)d_in[5];
  const float* sp_be = (const float*)d_in[6];
  const float* sp_m = (const float*)d_in[7];
  const float* sp_v = (const float*)d_in[8];
  const float* dn_w = (const float*)d_in[9];
  const float* dn_b = (const float*)d_in[10];
  const float* dn_g = (const float*)d_in[11];
  const float* dn_be = (const float*)d_in[12];
  const float* dn_m = (const float*)d_in[13];
  const float* dn_v = (const float*)d_in[14];

  float* out = (float*)d_out;
  float* out_sf = out;                                   // [16][1024][16]
  float* out_df = out + (size_t)BS * SPO * NS2;          // [16][1024][512]
  float* out_stk = out_df + (size_t)BS * DNO * 512;      // [16][512][16]
  // K2 partials live in the out_df region (8.4 MB << 33.5 MB); k2b consumes
  // them before k3 overwrites out_df — safe by stream ordering.
  float* part = out_df;

  int* fps_idx = (int*)((char*)d_ws + WS_FPS_OFF);
  int* knn_sel = (int*)((char*)d_ws + WS_KNN_OFF);
  unsigned short* wt = (unsigned short*)((char*)d_ws + WS_WT_OFF);

  hipLaunchKernelGGL(k0_wt, dim3(1536), dim3(256), 0, stream, dn_w, wt);
  hipLaunchKernelGGL(k1_fps_knn, dim3(BS), dim3(256), 0, stream,
                     stk_fea, out_stk, fps_idx, knn_sel);
  hipLaunchKernelGGL(k2a_partial, dim3(8, 8, 8), dim3(256), 0, stream,
                     sparse_fea, sp_w, knn_sel, part);
  hipLaunchKernelGGL(k2b_reduce, dim3(1024), dim3(256), 0, stream,
                     part, sp_b, sp_g, sp_be, sp_m, sp_v, out_sf);
  hipLaunchKernelGGL(k3_dense_mfma, dim3(512), dim3(512), 0, stream,
                     dense_fea, wt, dn_b, dn_g, dn_be, dn_m, dn_v, knn_sel,
                     out_df);
}